// Round 13
// baseline (57.764 us; speedup 1.0000x reference)
//
#include <hip/hip_runtime.h>

// eTofts model: B=8, T=60, H=W=256.
//   params[B,3,H,W], Cp[B,T], S0[B,1,H,W], T1[B,1,H,W] -> St[B,T,H,W] fp32
//
// Session knowledge:
//  - Incompressible write ceiling (R9 probe): 5.65 TB/s. Fill's 7.09 = const-
//    data artifact. FETCH~0 on full-line stores => no RFO.
//  - Effective-BW ladder vs per-wave contiguous run length:
//    256B=3.6, 1KB=4.4 (R11, 31.1us), 4KB=5.08 TB/s (R4, but +42MB re-reads).
//  - CHUNKS=1 minimizes traffic (136 MB, inputs read once).
// R13 = R12 fixed (R12 had a 4x stride bug -> OOB crash): 4KB runs +
// CHUNKS=1. 128 blocks x 256 thr x 16 px; block covers 4096 px:
// pixw = blk*4096 + w*1024 + lane*4, q-groups at +q*256 floats (1KB each).

#define N_TIME 60
#define HW (256 * 256)
#define TPB 256
#define GRID 128     // 524288 px / (256 thr * 16 px)

typedef float f32x4 __attribute__((ext_vector_type(4)));

__global__ __launch_bounds__(TPB) void etofts_kernel(
    const float* __restrict__ params,  // [B,3,H,W]
    const float* __restrict__ Cp,      // [B,T]
    const float* __restrict__ S0,      // [B,1,H,W]
    const float* __restrict__ T1,      // [B,1,H,W]
    float* __restrict__ out)           // [B,T,H,W]
{
    const float DT     = 5.0f;
    const float TR     = 5.0f;
    const float EPS    = 1e-8f;
    const float COS_FA = 0.9848077530122081f;            // cos(10 deg)
    const float QC2    = 0.0225f * 1.4426950408889634f;  // (R1*TR/1000)*log2(e)

    // 128 blocks: 16 per batch. Block-uniform -> Cp is scalar s_load.
    const int bx  = blockIdx.x;
    const int b   = bx >> 4;
    const int blk = bx & 15;

    // Block covers 4096 px; wave w owns 1024 px = 4 KB contiguous per frame.
    const int w    = threadIdx.x >> 6;
    const int lane = threadIdx.x & 63;
    const int pixw = blk * 4096 + w * 1024 + lane * 4;   // + q*256

    const float* p0 = params + ((size_t)b * 3 + 0) * HW + pixw;
    const float* p1 = params + ((size_t)b * 3 + 1) * HW + pixw;
    const float* p2 = params + ((size_t)b * 3 + 2) * HW + pixw;
    const float* ps = S0 + (size_t)b * HW + pixw;
    const float* pt = T1 + (size_t)b * HW + pixw;

    float Kt[16], vp[16], decay[16], Ce[16], eP[16], Kc[16], d0[16], d1[16];

#pragma unroll
    for (int q = 0; q < 4; ++q) {
        const float4 kt4 = *reinterpret_cast<const float4*>(p0 + q * 256);
        const float4 vp4 = *reinterpret_cast<const float4*>(p1 + q * 256);
        const float4 ve4 = *reinterpret_cast<const float4*>(p2 + q * 256);
        const float4 s04 = *reinterpret_cast<const float4*>(ps + q * 256);
        const float4 t14 = *reinterpret_cast<const float4*>(pt + q * 256);
        const float ktv[4] = {kt4.x, kt4.y, kt4.z, kt4.w};
        const float vpv[4] = {vp4.x, vp4.y, vp4.z, vp4.w};
        const float vev[4] = {ve4.x, ve4.y, ve4.z, ve4.w};
        const float s0v[4] = {s04.x, s04.y, s04.z, s04.w};
        const float t1v[4] = {t14.x, t14.y, t14.z, t14.w};
#pragma unroll
        for (int i = 0; i < 4; ++i) {
            const int j = q * 4 + i;
            const float Ktrans = ktv[i] * (1.0f / 60.0f);
            const float Kep    = __fdividef(Ktrans, vev[i] + EPS);
            Kt[j]    = Ktrans;
            vp[j]    = vpv[i];
            decay[j] = __expf(-Kep * DT);
            const float P = __fdividef(TR, t1v[i] + EPS);
            const float e = __expf(-P);
            eP[j] = e;
            Kc[j] = (1.0f - COS_FA * e) * s0v[i];
            const float den1 = 1.0f - e;
            d0[j] = den1 + EPS;              // den = d0 - d1*ePQ
            d1[j] = COS_FA * den1;
            Ce[j] = 0.0f;
        }
    }

    const float* cp_row = Cp + b * N_TIME;   // uniform -> scalar s_load
    float* outp = out + ((size_t)b * N_TIME) * HW + pixw;

    // Wave's 4 stores per frame land at +0,+1KB,+2KB,+3KB: one 4 KB
    // contiguous run per wave per frame (the R4-proven efficient granule).
#pragma unroll 2
    for (int t = 0; t < N_TIME; ++t) {
        const float cp   = cp_row[t];
        const float cpdt = cp * DT;
        float* op = outp + (size_t)t * HW;
#pragma unroll
        for (int q = 0; q < 4; ++q) {
            float st[4];
#pragma unroll
            for (int i = 0; i < 4; ++i) {
                const int j = q * 4 + i;
                Ce[j] = Ce[j] * decay[j] + cpdt;
                const float Ct  = vp[j] * cp + Kt[j] * Ce[j];
                const float ePQ = eP[j] * exp2f(-QC2 * Ct);
                const float num = Kc[j] - Kc[j] * ePQ;
                const float den = d0[j] - d1[j] * ePQ;
                st[i] = __fdividef(num, den);
            }
            f32x4 v = {st[0], st[1], st[2], st[3]};
            __builtin_nontemporal_store(v, reinterpret_cast<f32x4*>(op + q * 256));
        }
    }
}

extern "C" void kernel_launch(void* const* d_in, const int* in_sizes, int n_in,
                              void* d_out, int out_size, void* d_ws, size_t ws_size,
                              hipStream_t stream) {
    const float* params = (const float*)d_in[0];
    const float* Cp     = (const float*)d_in[1];
    const float* S0     = (const float*)d_in[2];
    const float* T1     = (const float*)d_in[3];
    float* out          = (float*)d_out;

    etofts_kernel<<<GRID, TPB, 0, stream>>>(params, Cp, S0, T1, out);
}